// Round 1
// baseline (737.776 us; speedup 1.0000x reference)
//
#include <hip/hip_runtime.h>
#include <math.h>

#define D_MODEL 512
#define NHEADS  8
#define DHEAD   64
#define NSEQ    2048
#define BMQ     128
#define BNK     128
#define NBLKS   (NSEQ / BMQ)   // 16
#define EPSF    1e-6f

// ---------------------------------------------------------------------------
// fp32 tiled GEMM body: C[bm:bm+64][bn:bn+64] = A[.,K] @ W[K,N] + bias
// 256 threads, 4x4 outputs per thread, K-step 32.
__device__ __forceinline__ void gemm_body(const float* __restrict__ A,
                                          const float* __restrict__ W,
                                          const float* __restrict__ bias,
                                          float* __restrict__ C,
                                          int K, int N, int bm, int bn)
{
  __shared__ float As[32][68];   // A^T tile: As[kk][m]
  __shared__ float Ws[32][68];   // Ws[kk][n]
  const int tid = threadIdx.x;
  const int ty = tid >> 4, tx = tid & 15;
  float acc[4][4] = {{0.f, 0.f, 0.f, 0.f}};
  for (int k0 = 0; k0 < K; k0 += 32) {
#pragma unroll
    for (int l = 0; l < 2; ++l) {
      int idx = tid + l * 256;            // f4 index over 64 rows x 8 f4
      int r = idx >> 3, c4 = idx & 7;
      float4 a = *reinterpret_cast<const float4*>(&A[(size_t)(bm + r) * K + k0 + c4 * 4]);
      As[c4 * 4 + 0][r] = a.x;
      As[c4 * 4 + 1][r] = a.y;
      As[c4 * 4 + 2][r] = a.z;
      As[c4 * 4 + 3][r] = a.w;
    }
#pragma unroll
    for (int l = 0; l < 2; ++l) {
      int idx = tid + l * 256;            // f4 index over 32 rows x 16 f4
      int kk = idx >> 4, c4 = idx & 15;
      *reinterpret_cast<float4*>(&Ws[kk][c4 * 4]) =
          *reinterpret_cast<const float4*>(&W[(size_t)(k0 + kk) * N + bn + c4 * 4]);
    }
    __syncthreads();
#pragma unroll
    for (int kk = 0; kk < 32; ++kk) {
      float4 a = *reinterpret_cast<const float4*>(&As[kk][ty * 4]);
      float4 w = *reinterpret_cast<const float4*>(&Ws[kk][tx * 4]);
      float av[4] = {a.x, a.y, a.z, a.w};
      float wv[4] = {w.x, w.y, w.z, w.w};
#pragma unroll
      for (int i = 0; i < 4; ++i)
#pragma unroll
        for (int j = 0; j < 4; ++j)
          acc[i][j] = fmaf(av[i], wv[j], acc[i][j]);
    }
    __syncthreads();
  }
#pragma unroll
  for (int i = 0; i < 4; ++i) {
    int rr = bm + ty * 4 + i;
    int cn = bn + tx * 4;
    float4 o;
    o.x = acc[i][0] + bias[cn + 0];
    o.y = acc[i][1] + bias[cn + 1];
    o.z = acc[i][2] + bias[cn + 2];
    o.w = acc[i][3] + bias[cn + 3];
    *reinterpret_cast<float4*>(&C[(size_t)rr * N + cn]) = o;
  }
}

// Q/K/V projection: grid (N/64, M/64, 3)
__global__ __launch_bounds__(256) void qkv_kernel(
    const float* __restrict__ x,
    const float* __restrict__ Wq, const float* __restrict__ bq,
    const float* __restrict__ Wk, const float* __restrict__ bk,
    const float* __restrict__ Wv, const float* __restrict__ bv,
    float* __restrict__ Q, float* __restrict__ K, float* __restrict__ V)
{
  const int z = blockIdx.z;
  const float* W = (z == 0) ? Wq : (z == 1) ? Wk : Wv;
  const float* b = (z == 0) ? bq : (z == 1) ? bk : bv;
  float*       C = (z == 0) ? Q  : (z == 1) ? K  : V;
  gemm_body(x, W, b, C, D_MODEL, D_MODEL, blockIdx.y * 64, blockIdx.x * 64);
}

// Output projection: grid (N/64, M/64)
__global__ __launch_bounds__(256) void oproj_kernel(
    const float* __restrict__ A, const float* __restrict__ Wo,
    const float* __restrict__ bo, float* __restrict__ C)
{
  gemm_body(A, Wo, bo, C, D_MODEL, D_MODEL, blockIdx.y * 64, blockIdx.x * 64);
}

// ---------------------------------------------------------------------------
// Poincare block-softmax attention. grid = (NBLKS, NHEADS), 256 threads.
// Thread (ty = tid>>4 in 0..15, tx = tid&15).
// Score phase:  rows 16*i+ty (i<8), cols 16*j+tx (j<8)  -> 8x8 frag.
// eV phase:     rows 16*i+ty (i<8), cols 4*tx..4*tx+3   -> 8x4 acc.
__global__ __launch_bounds__(256, 1) void attn_kernel(
    const float* __restrict__ Q, const float* __restrict__ K,
    const float* __restrict__ V, const float* __restrict__ cptr,
    float* __restrict__ O)
{
  __shared__ float Qs[BMQ][68];
  __shared__ float KVs[BNK][68];
  __shared__ float Es[BMQ][132];

  const int m  = blockIdx.x;
  const int h  = blockIdx.y;
  const int tid = threadIdx.x;
  const int ty = tid >> 4;
  const int tx = tid & 15;

  const float cc = fmaxf(fabsf(cptr[0]), 1e-6f);
  const float inv_sqrt_c = rsqrtf(cc);
  const float two_cc = 2.f * cc;

  // ---- load Q tile (rows m*128.., head cols) ----
  const float* Qg = Q + (size_t)m * BMQ * D_MODEL + h * DHEAD;
#pragma unroll
  for (int l = 0; l < 8; ++l) {
    int idx = tid + l * 256;            // f4 index over 128 rows x 16 f4
    int r = idx >> 4, c4 = idx & 15;
    *reinterpret_cast<float4*>(&Qs[r][c4 * 4]) =
        *reinterpret_cast<const float4*>(&Qg[(size_t)r * D_MODEL + c4 * 4]);
  }
  __syncthreads();

  // per-thread row norms (rows 16*i+ty)
  float qn[8], qa[8];
#pragma unroll
  for (int i = 0; i < 8; ++i) {
    int r = 16 * i + ty;
    float s = 0.f;
#pragma unroll
    for (int d4 = 0; d4 < 16; ++d4) {
      float4 q = *reinterpret_cast<const float4*>(&Qs[r][d4 * 4]);
      s += q.x * q.x + q.y * q.y + q.z * q.z + q.w * q.w;
    }
    qn[i] = s;
    qa[i] = 1.f - cc * s;
  }

  float acc[8][4] = {{0.f}};
  float norm[8] = {0.f};

  for (int n = 0; n <= m; ++n) {
    __syncthreads();                    // previous eV readers of KVs done
    // ---- load K tile ----
    {
      const float* Kg = K + (size_t)n * BNK * D_MODEL + h * DHEAD;
#pragma unroll
      for (int l = 0; l < 8; ++l) {
        int idx = tid + l * 256;
        int r = idx >> 4, c4 = idx & 15;
        *reinterpret_cast<float4*>(&KVs[r][c4 * 4]) =
            *reinterpret_cast<const float4*>(&Kg[(size_t)r * D_MODEL + c4 * 4]);
      }
    }
    __syncthreads();

    // ---- S = Q.K^T fragment + k norms ----
    float s[8][8] = {{0.f}};
    float kn[8] = {0.f};
#pragma unroll
    for (int d4 = 0; d4 < 16; ++d4) {
      float4 kv[8];
#pragma unroll
      for (int j = 0; j < 8; ++j) {
        kv[j] = *reinterpret_cast<const float4*>(&KVs[16 * j + tx][d4 * 4]);
        kn[j] += kv[j].x * kv[j].x + kv[j].y * kv[j].y + kv[j].z * kv[j].z + kv[j].w * kv[j].w;
      }
#pragma unroll
      for (int i = 0; i < 8; ++i) {
        float4 qv = *reinterpret_cast<const float4*>(&Qs[16 * i + ty][d4 * 4]);
#pragma unroll
        for (int j = 0; j < 8; ++j) {
          s[i][j] = fmaf(qv.x, kv[j].x, s[i][j]);
          s[i][j] = fmaf(qv.y, kv[j].y, s[i][j]);
          s[i][j] = fmaf(qv.z, kv[j].z, s[i][j]);
          s[i][j] = fmaf(qv.w, kv[j].w, s[i][j]);
        }
      }
    }
    float ka[8];
#pragma unroll
    for (int j = 0; j < 8; ++j) ka[j] = 1.f - cc * kn[j];

    // ---- Poincare scores + causal-diag mask + per-block row max ----
    const bool diag = (n == m);
    float mloc[8];
#pragma unroll
    for (int i = 0; i < 8; ++i) {
      const int r = 16 * i + ty;        // local row
      float mi = -INFINITY;
#pragma unroll
      for (int j = 0; j < 8; ++j) {
        const int cl = 16 * j + tx;     // local col
        float dsq = fmaxf(qn[i] + kn[j] - 2.f * s[i][j], 0.f);
        float den = fmaxf(qa[i] * ka[j], EPSF);
        float arg = fmaxf(fmaf(two_cc, dsq / den, 1.f), 1.f + EPSF);
        float sc  = -acoshf(arg) * inv_sqrt_c;
        if (diag && cl > r) sc = -INFINITY;
        s[i][j] = sc;
        mi = fmaxf(mi, sc);
      }
      mloc[i] = mi;
    }
#pragma unroll
    for (int d = 1; d < 16; d <<= 1)
#pragma unroll
      for (int i = 0; i < 8; ++i)
        mloc[i] = fmaxf(mloc[i], __shfl_xor(mloc[i], d, 64));

    // ---- e = exp(s - bmax), norm accumulate, write to LDS ----
#pragma unroll
    for (int i = 0; i < 8; ++i) {
      const int r = 16 * i + ty;
#pragma unroll
      for (int j = 0; j < 8; ++j) {
        const int cl = 16 * j + tx;
        float ev = (diag && cl > r) ? 0.f : expf(s[i][j] - mloc[i]);
        norm[i] += ev;
        Es[r][cl] = ev;
      }
    }
    __syncthreads();                    // Es complete; all KVs(K) reads done

    // ---- load V tile over K tile ----
    {
      const float* Vg = V + (size_t)n * BNK * D_MODEL + h * DHEAD;
#pragma unroll
      for (int l = 0; l < 8; ++l) {
        int idx = tid + l * 256;
        int r = idx >> 4, c4 = idx & 15;
        *reinterpret_cast<float4*>(&KVs[r][c4 * 4]) =
            *reinterpret_cast<const float4*>(&Vg[(size_t)r * D_MODEL + c4 * 4]);
      }
    }
    __syncthreads();

    // ---- acc += E @ V  (rows 16*i+ty, cols 4*tx..) ----
    for (int nn = 0; nn < BNK; nn += 4) {
      float4 v0 = *reinterpret_cast<const float4*>(&KVs[nn + 0][tx * 4]);
      float4 v1 = *reinterpret_cast<const float4*>(&KVs[nn + 1][tx * 4]);
      float4 v2 = *reinterpret_cast<const float4*>(&KVs[nn + 2][tx * 4]);
      float4 v3 = *reinterpret_cast<const float4*>(&KVs[nn + 3][tx * 4]);
#pragma unroll
      for (int i = 0; i < 8; ++i) {
        float4 ep = *reinterpret_cast<const float4*>(&Es[16 * i + ty][nn]);
        acc[i][0] = fmaf(ep.x, v0.x, fmaf(ep.y, v1.x, fmaf(ep.z, v2.x, fmaf(ep.w, v3.x, acc[i][0]))));
        acc[i][1] = fmaf(ep.x, v0.y, fmaf(ep.y, v1.y, fmaf(ep.z, v2.y, fmaf(ep.w, v3.y, acc[i][1]))));
        acc[i][2] = fmaf(ep.x, v0.z, fmaf(ep.y, v1.z, fmaf(ep.z, v2.z, fmaf(ep.w, v3.z, acc[i][2]))));
        acc[i][3] = fmaf(ep.x, v0.w, fmaf(ep.y, v1.w, fmaf(ep.z, v2.w, fmaf(ep.w, v3.w, acc[i][3]))));
      }
    }
  }

  // ---- normalizer reduce across the 16 tx lanes, divide, store ----
#pragma unroll
  for (int d = 1; d < 16; d <<= 1)
#pragma unroll
    for (int i = 0; i < 8; ++i)
      norm[i] += __shfl_xor(norm[i], d, 64);

  float* Og = O + (size_t)m * BMQ * D_MODEL + h * DHEAD;
#pragma unroll
  for (int i = 0; i < 8; ++i) {
    int r = 16 * i + ty;
    float inv = 1.f / fmaxf(norm[i], EPSF);
    float4 o;
    o.x = acc[i][0] * inv;
    o.y = acc[i][1] * inv;
    o.z = acc[i][2] * inv;
    o.w = acc[i][3] * inv;
    *reinterpret_cast<float4*>(&Og[(size_t)r * D_MODEL + tx * 4]) = o;
  }
}

// ---------------------------------------------------------------------------
extern "C" void kernel_launch(void* const* d_in, const int* in_sizes, int n_in,
                              void* d_out, int out_size, void* d_ws, size_t ws_size,
                              hipStream_t stream) {
  (void)in_sizes; (void)n_in; (void)out_size; (void)ws_size;
  const float* x  = (const float*)d_in[0];
  const float* c  = (const float*)d_in[1];
  const float* Wq = (const float*)d_in[2];
  const float* bq = (const float*)d_in[3];
  const float* Wk = (const float*)d_in[4];
  const float* bk = (const float*)d_in[5];
  const float* Wv = (const float*)d_in[6];
  const float* bv = (const float*)d_in[7];
  const float* Wo = (const float*)d_in[8];
  const float* bo = (const float*)d_in[9];
  float* out = (float*)d_out;

  float* Q = (float*)d_ws;                     // 2048*512 f32 = 4 MiB
  float* K = Q + (size_t)NSEQ * D_MODEL;
  float* V = K + (size_t)NSEQ * D_MODEL;
  float* O = V + (size_t)NSEQ * D_MODEL;       // total 16 MiB of d_ws

  qkv_kernel<<<dim3(D_MODEL / 64, NSEQ / 64, 3), 256, 0, stream>>>(
      x, Wq, bq, Wk, bk, Wv, bv, Q, K, V);
  attn_kernel<<<dim3(NBLKS, NHEADS), 256, 0, stream>>>(Q, K, V, c, O);
  oproj_kernel<<<dim3(D_MODEL / 64, NSEQ / 64), 256, 0, stream>>>(O, Wo, bo, out);
}

// Round 2
// 348.157 us; speedup vs baseline: 2.1191x; 2.1191x over previous
//
#include <hip/hip_runtime.h>
#include <math.h>

#define D_MODEL 512
#define NHEADS  8
#define DHEAD   64
#define NSEQ    2048
#define BMQ     128
#define BNK     128
#define NBLKS   (NSEQ / BMQ)   // 16
#define NPAIR   (NBLKS * (NBLKS + 1) / 2)  // 136 causal block pairs
#define EPSF    1e-6f

// ---------------------------------------------------------------------------
// fp32 tiled GEMM body: C[bm:bm+64][bn:bn+64] = A[.,K] @ W[K,N] + bias
__device__ __forceinline__ void gemm_body(const float* __restrict__ A,
                                          const float* __restrict__ W,
                                          const float* __restrict__ bias,
                                          float* __restrict__ C,
                                          int K, int N, int bm, int bn)
{
  __shared__ float As[32][68];   // A^T tile: As[kk][m]
  __shared__ float Ws[32][68];   // Ws[kk][n]
  const int tid = threadIdx.x;
  const int ty = tid >> 4, tx = tid & 15;
  float acc[4][4] = {{0.f, 0.f, 0.f, 0.f}};
  for (int k0 = 0; k0 < K; k0 += 32) {
#pragma unroll
    for (int l = 0; l < 2; ++l) {
      int idx = tid + l * 256;            // f4 index over 64 rows x 8 f4
      int r = idx >> 3, c4 = idx & 7;
      float4 a = *reinterpret_cast<const float4*>(&A[(size_t)(bm + r) * K + k0 + c4 * 4]);
      As[c4 * 4 + 0][r] = a.x;
      As[c4 * 4 + 1][r] = a.y;
      As[c4 * 4 + 2][r] = a.z;
      As[c4 * 4 + 3][r] = a.w;
    }
#pragma unroll
    for (int l = 0; l < 2; ++l) {
      int idx = tid + l * 256;            // f4 index over 32 rows x 16 f4
      int kk = idx >> 4, c4 = idx & 15;
      *reinterpret_cast<float4*>(&Ws[kk][c4 * 4]) =
          *reinterpret_cast<const float4*>(&W[(size_t)(k0 + kk) * N + bn + c4 * 4]);
    }
    __syncthreads();
#pragma unroll
    for (int kk = 0; kk < 32; ++kk) {
      float4 a = *reinterpret_cast<const float4*>(&As[kk][ty * 4]);
      float4 w = *reinterpret_cast<const float4*>(&Ws[kk][tx * 4]);
      float av[4] = {a.x, a.y, a.z, a.w};
      float wv[4] = {w.x, w.y, w.z, w.w};
#pragma unroll
      for (int i = 0; i < 4; ++i)
#pragma unroll
        for (int j = 0; j < 4; ++j)
          acc[i][j] = fmaf(av[i], wv[j], acc[i][j]);
    }
    __syncthreads();
  }
#pragma unroll
  for (int i = 0; i < 4; ++i) {
    int rr = bm + ty * 4 + i;
    int cn = bn + tx * 4;
    float4 o;
    o.x = acc[i][0] + bias[cn + 0];
    o.y = acc[i][1] + bias[cn + 1];
    o.z = acc[i][2] + bias[cn + 2];
    o.w = acc[i][3] + bias[cn + 3];
    *reinterpret_cast<float4*>(&C[(size_t)rr * N + cn]) = o;
  }
}

__global__ __launch_bounds__(256) void qkv_kernel(
    const float* __restrict__ x,
    const float* __restrict__ Wq, const float* __restrict__ bq,
    const float* __restrict__ Wk, const float* __restrict__ bk,
    const float* __restrict__ Wv, const float* __restrict__ bv,
    float* __restrict__ Q, float* __restrict__ K, float* __restrict__ V)
{
  const int z = blockIdx.z;
  const float* W = (z == 0) ? Wq : (z == 1) ? Wk : Wv;
  const float* b = (z == 0) ? bq : (z == 1) ? bk : bv;
  float*       C = (z == 0) ? Q  : (z == 1) ? K  : V;
  gemm_body(x, W, b, C, D_MODEL, D_MODEL, blockIdx.y * 64, blockIdx.x * 64);
}

__global__ __launch_bounds__(256) void oproj_kernel(
    const float* __restrict__ A, const float* __restrict__ Wo,
    const float* __restrict__ bo, float* __restrict__ C)
{
  gemm_body(A, Wo, bo, C, D_MODEL, D_MODEL, blockIdx.y * 64, blockIdx.x * 64);
}

// ---------------------------------------------------------------------------
// One workgroup per (block-pair, head). 512 threads (8 waves).
// ty = tid>>4 (0..31), tx = tid&15.
// Score frag: rows 32*i+ty (i<4), cols 16*j+tx (j<8).
// eV frag:    rows 32*i+ty (i<4), cols 4*tx..4*tx+3.
__global__ __launch_bounds__(512, 1) void attn_pair_kernel(
    const float* __restrict__ Q, const float* __restrict__ K,
    const float* __restrict__ V, const float* __restrict__ cptr,
    float* __restrict__ Opart, float* __restrict__ Npart)
{
  __shared__ float Qs[BMQ][68];
  __shared__ float KVs[BNK][68];
  __shared__ float Es[BMQ][132];

  const int pid = blockIdx.x;
  const int h   = blockIdx.y;
  int m = (int)floorf((sqrtf(8.f * (float)pid + 1.f) - 1.f) * 0.5f);
  while ((m + 1) * (m + 2) / 2 <= pid) ++m;
  while (m * (m + 1) / 2 > pid) --m;
  const int n = pid - m * (m + 1) / 2;

  const int tid = threadIdx.x;
  const int ty = tid >> 4;
  const int tx = tid & 15;

  const float cc = fmaxf(fabsf(cptr[0]), 1e-6f);
  const float inv_sqrt_c = rsqrtf(cc);
  const float two_cc = 2.f * cc;

  const float* Qg = Q + (size_t)m * BMQ * D_MODEL + h * DHEAD;
  const float* Kg = K + (size_t)n * BNK * D_MODEL + h * DHEAD;
#pragma unroll
  for (int l = 0; l < 4; ++l) {
    int idx = tid + l * 512;            // f4 index over 128 rows x 16 f4
    int r = idx >> 4, c4 = idx & 15;
    *reinterpret_cast<float4*>(&Qs[r][c4 * 4]) =
        *reinterpret_cast<const float4*>(&Qg[(size_t)r * D_MODEL + c4 * 4]);
    *reinterpret_cast<float4*>(&KVs[r][c4 * 4]) =
        *reinterpret_cast<const float4*>(&Kg[(size_t)r * D_MODEL + c4 * 4]);
  }
  __syncthreads();

  // q norms for this thread's 4 rows
  float qn[4], qa[4];
#pragma unroll
  for (int i = 0; i < 4; ++i) {
    int r = 32 * i + ty;
    float s = 0.f;
#pragma unroll
    for (int d4 = 0; d4 < 16; ++d4) {
      float4 q = *reinterpret_cast<const float4*>(&Qs[r][d4 * 4]);
      s += q.x * q.x + q.y * q.y + q.z * q.z + q.w * q.w;
    }
    qn[i] = s;
    qa[i] = 1.f - cc * s;
  }

  // ---- S = Q.K^T fragment + k norms ----
  float s[4][8] = {{0.f}};
  float kn[8] = {0.f};
#pragma unroll
  for (int d4 = 0; d4 < 16; ++d4) {
    float4 kv[8];
#pragma unroll
    for (int j = 0; j < 8; ++j) {
      kv[j] = *reinterpret_cast<const float4*>(&KVs[16 * j + tx][d4 * 4]);
      kn[j] += kv[j].x * kv[j].x + kv[j].y * kv[j].y + kv[j].z * kv[j].z + kv[j].w * kv[j].w;
    }
#pragma unroll
    for (int i = 0; i < 4; ++i) {
      float4 qv = *reinterpret_cast<const float4*>(&Qs[32 * i + ty][d4 * 4]);
#pragma unroll
      for (int j = 0; j < 8; ++j) {
        s[i][j] = fmaf(qv.x, kv[j].x, s[i][j]);
        s[i][j] = fmaf(qv.y, kv[j].y, s[i][j]);
        s[i][j] = fmaf(qv.z, kv[j].z, s[i][j]);
        s[i][j] = fmaf(qv.w, kv[j].w, s[i][j]);
      }
    }
  }
  float ka[8];
#pragma unroll
  for (int j = 0; j < 8; ++j) ka[j] = 1.f - cc * kn[j];

  // ---- Poincare scores + causal-diag mask + per-block row max ----
  const bool diag = (n == m);
  float mloc[4];
#pragma unroll
  for (int i = 0; i < 4; ++i) {
    const int r = 32 * i + ty;
    float mi = -INFINITY;
#pragma unroll
    for (int j = 0; j < 8; ++j) {
      const int cl = 16 * j + tx;
      float dsq = fmaxf(qn[i] + kn[j] - 2.f * s[i][j], 0.f);
      float den = fmaxf(qa[i] * ka[j], EPSF);
      float arg = fmaxf(fmaf(two_cc, dsq / den, 1.f), 1.f + EPSF);
      float sc  = -acoshf(arg) * inv_sqrt_c;
      if (diag && cl > r) sc = -INFINITY;
      s[i][j] = sc;
      mi = fmaxf(mi, sc);
    }
    mloc[i] = mi;
  }
#pragma unroll
  for (int d = 1; d < 16; d <<= 1)
#pragma unroll
    for (int i = 0; i < 4; ++i)
      mloc[i] = fmaxf(mloc[i], __shfl_xor(mloc[i], d, 64));

  float norm[4] = {0.f, 0.f, 0.f, 0.f};
#pragma unroll
  for (int i = 0; i < 4; ++i) {
    const int r = 32 * i + ty;
#pragma unroll
    for (int j = 0; j < 8; ++j) {
      const int cl = 16 * j + tx;
      float ev = (diag && cl > r) ? 0.f : expf(s[i][j] - mloc[i]);
      norm[i] += ev;
      Es[r][cl] = ev;
    }
  }
  __syncthreads();                      // Es complete; KVs(K) reads done

  // ---- load V tile over K tile ----
  const float* Vg = V + (size_t)n * BNK * D_MODEL + h * DHEAD;
#pragma unroll
  for (int l = 0; l < 4; ++l) {
    int idx = tid + l * 512;
    int r = idx >> 4, c4 = idx & 15;
    *reinterpret_cast<float4*>(&KVs[r][c4 * 4]) =
        *reinterpret_cast<const float4*>(&Vg[(size_t)r * D_MODEL + c4 * 4]);
  }
  __syncthreads();

  // ---- acc = E @ V ----
  float acc[4][4] = {{0.f}};
  for (int nn = 0; nn < BNK; nn += 4) {
    float4 v0 = *reinterpret_cast<const float4*>(&KVs[nn + 0][tx * 4]);
    float4 v1 = *reinterpret_cast<const float4*>(&KVs[nn + 1][tx * 4]);
    float4 v2 = *reinterpret_cast<const float4*>(&KVs[nn + 2][tx * 4]);
    float4 v3 = *reinterpret_cast<const float4*>(&KVs[nn + 3][tx * 4]);
#pragma unroll
    for (int i = 0; i < 4; ++i) {
      float4 ep = *reinterpret_cast<const float4*>(&Es[32 * i + ty][nn]);
      acc[i][0] = fmaf(ep.x, v0.x, fmaf(ep.y, v1.x, fmaf(ep.z, v2.x, fmaf(ep.w, v3.x, acc[i][0]))));
      acc[i][1] = fmaf(ep.x, v0.y, fmaf(ep.y, v1.y, fmaf(ep.z, v2.y, fmaf(ep.w, v3.y, acc[i][1]))));
      acc[i][2] = fmaf(ep.x, v0.z, fmaf(ep.y, v1.z, fmaf(ep.z, v2.z, fmaf(ep.w, v3.z, acc[i][2]))));
      acc[i][3] = fmaf(ep.x, v0.w, fmaf(ep.y, v1.w, fmaf(ep.z, v2.w, fmaf(ep.w, v3.w, acc[i][3]))));
    }
  }

  // ---- norm reduce across tx, write partials ----
#pragma unroll
  for (int d = 1; d < 16; d <<= 1)
#pragma unroll
    for (int i = 0; i < 4; ++i)
      norm[i] += __shfl_xor(norm[i], d, 64);

  const size_t pbase = (size_t)h * NPAIR + pid;
  float* Op = Opart + pbase * (BMQ * DHEAD);
#pragma unroll
  for (int i = 0; i < 4; ++i) {
    int r = 32 * i + ty;
    float4 o;
    o.x = acc[i][0]; o.y = acc[i][1]; o.z = acc[i][2]; o.w = acc[i][3];
    *reinterpret_cast<float4*>(&Op[(size_t)r * DHEAD + tx * 4]) = o;
    if (tx == 0) Npart[pbase * BMQ + r] = norm[i];
  }
}

// ---------------------------------------------------------------------------
// Reduce partials over n for each (m,h): out = (sum_n Opart) / clip(sum_n Npart)
__global__ __launch_bounds__(256) void reduce_kernel(
    const float* __restrict__ Opart, const float* __restrict__ Npart,
    float* __restrict__ O)
{
  const int m = blockIdx.x;
  const int h = blockIdx.y;
  const int tid = threadIdx.x;
  const int base = m * (m + 1) / 2;

  __shared__ float innorm[BMQ];
  if (tid < BMQ) {
    float s = 0.f;
    for (int n = 0; n <= m; ++n)
      s += Npart[((size_t)h * NPAIR + base + n) * BMQ + tid];
    innorm[tid] = 1.f / fmaxf(s, EPSF);
  }
  __syncthreads();

#pragma unroll
  for (int k = 0; k < 8; ++k) {
    int f = tid + k * 256;              // f4 index over 128 rows x 16 f4
    int r = f >> 4, c4 = f & 15;
    float4 s = {0.f, 0.f, 0.f, 0.f};
    for (int n = 0; n <= m; ++n) {
      const float4 p = *reinterpret_cast<const float4*>(
          &Opart[((size_t)h * NPAIR + base + n) * (BMQ * DHEAD) + (size_t)f * 4]);
      s.x += p.x; s.y += p.y; s.z += p.z; s.w += p.w;
    }
    float inv = innorm[r];
    s.x *= inv; s.y *= inv; s.z *= inv; s.w *= inv;
    *reinterpret_cast<float4*>(
        &O[((size_t)(m * BMQ + r)) * D_MODEL + h * DHEAD + c4 * 4]) = s;
  }
}

// ---------------------------------------------------------------------------
// R1 fallback (single workgroup per (m,h), serial over n) — used only if the
// workspace is too small for the partial buffers.
__global__ __launch_bounds__(256, 1) void attn_kernel(
    const float* __restrict__ Q, const float* __restrict__ K,
    const float* __restrict__ V, const float* __restrict__ cptr,
    float* __restrict__ O)
{
  __shared__ float Qs[BMQ][68];
  __shared__ float KVs[BNK][68];
  __shared__ float Es[BMQ][132];

  const int m  = blockIdx.x;
  const int h  = blockIdx.y;
  const int tid = threadIdx.x;
  const int ty = tid >> 4;
  const int tx = tid & 15;

  const float cc = fmaxf(fabsf(cptr[0]), 1e-6f);
  const float inv_sqrt_c = rsqrtf(cc);
  const float two_cc = 2.f * cc;

  const float* Qg = Q + (size_t)m * BMQ * D_MODEL + h * DHEAD;
#pragma unroll
  for (int l = 0; l < 8; ++l) {
    int idx = tid + l * 256;
    int r = idx >> 4, c4 = idx & 15;
    *reinterpret_cast<float4*>(&Qs[r][c4 * 4]) =
        *reinterpret_cast<const float4*>(&Qg[(size_t)r * D_MODEL + c4 * 4]);
  }
  __syncthreads();

  float qn[8], qa[8];
#pragma unroll
  for (int i = 0; i < 8; ++i) {
    int r = 16 * i + ty;
    float s = 0.f;
#pragma unroll
    for (int d4 = 0; d4 < 16; ++d4) {
      float4 q = *reinterpret_cast<const float4*>(&Qs[r][d4 * 4]);
      s += q.x * q.x + q.y * q.y + q.z * q.z + q.w * q.w;
    }
    qn[i] = s;
    qa[i] = 1.f - cc * s;
  }

  float acc[8][4] = {{0.f}};
  float norm[8] = {0.f};

  for (int n = 0; n <= m; ++n) {
    __syncthreads();
    {
      const float* Kg = K + (size_t)n * BNK * D_MODEL + h * DHEAD;
#pragma unroll
      for (int l = 0; l < 8; ++l) {
        int idx = tid + l * 256;
        int r = idx >> 4, c4 = idx & 15;
        *reinterpret_cast<float4*>(&KVs[r][c4 * 4]) =
            *reinterpret_cast<const float4*>(&Kg[(size_t)r * D_MODEL + c4 * 4]);
      }
    }
    __syncthreads();

    float s[8][8] = {{0.f}};
    float kn[8] = {0.f};
#pragma unroll
    for (int d4 = 0; d4 < 16; ++d4) {
      float4 kv[8];
#pragma unroll
      for (int j = 0; j < 8; ++j) {
        kv[j] = *reinterpret_cast<const float4*>(&KVs[16 * j + tx][d4 * 4]);
        kn[j] += kv[j].x * kv[j].x + kv[j].y * kv[j].y + kv[j].z * kv[j].z + kv[j].w * kv[j].w;
      }
#pragma unroll
      for (int i = 0; i < 8; ++i) {
        float4 qv = *reinterpret_cast<const float4*>(&Qs[16 * i + ty][d4 * 4]);
#pragma unroll
        for (int j = 0; j < 8; ++j) {
          s[i][j] = fmaf(qv.x, kv[j].x, s[i][j]);
          s[i][j] = fmaf(qv.y, kv[j].y, s[i][j]);
          s[i][j] = fmaf(qv.z, kv[j].z, s[i][j]);
          s[i][j] = fmaf(qv.w, kv[j].w, s[i][j]);
        }
      }
    }
    float ka[8];
#pragma unroll
    for (int j = 0; j < 8; ++j) ka[j] = 1.f - cc * kn[j];

    const bool diagb = (n == m);
    float mloc[8];
#pragma unroll
    for (int i = 0; i < 8; ++i) {
      const int r = 16 * i + ty;
      float mi = -INFINITY;
#pragma unroll
      for (int j = 0; j < 8; ++j) {
        const int cl = 16 * j + tx;
        float dsq = fmaxf(qn[i] + kn[j] - 2.f * s[i][j], 0.f);
        float den = fmaxf(qa[i] * ka[j], EPSF);
        float arg = fmaxf(fmaf(two_cc, dsq / den, 1.f), 1.f + EPSF);
        float sc  = -acoshf(arg) * inv_sqrt_c;
        if (diagb && cl > r) sc = -INFINITY;
        s[i][j] = sc;
        mi = fmaxf(mi, sc);
      }
      mloc[i] = mi;
    }
#pragma unroll
    for (int d = 1; d < 16; d <<= 1)
#pragma unroll
      for (int i = 0; i < 8; ++i)
        mloc[i] = fmaxf(mloc[i], __shfl_xor(mloc[i], d, 64));

#pragma unroll
    for (int i = 0; i < 8; ++i) {
      const int r = 16 * i + ty;
#pragma unroll
      for (int j = 0; j < 8; ++j) {
        const int cl = 16 * j + tx;
        float ev = (diagb && cl > r) ? 0.f : expf(s[i][j] - mloc[i]);
        norm[i] += ev;
        Es[r][cl] = ev;
      }
    }
    __syncthreads();

    {
      const float* Vg = V + (size_t)n * BNK * D_MODEL + h * DHEAD;
#pragma unroll
      for (int l = 0; l < 8; ++l) {
        int idx = tid + l * 256;
        int r = idx >> 4, c4 = idx & 15;
        *reinterpret_cast<float4*>(&KVs[r][c4 * 4]) =
            *reinterpret_cast<const float4*>(&Vg[(size_t)r * D_MODEL + c4 * 4]);
      }
    }
    __syncthreads();

    for (int nn = 0; nn < BNK; nn += 4) {
      float4 v0 = *reinterpret_cast<const float4*>(&KVs[nn + 0][tx * 4]);
      float4 v1 = *reinterpret_cast<const float4*>(&KVs[nn + 1][tx * 4]);
      float4 v2 = *reinterpret_cast<const float4*>(&KVs[nn + 2][tx * 4]);
      float4 v3 = *reinterpret_cast<const float4*>(&KVs[nn + 3][tx * 4]);
#pragma unroll
      for (int i = 0; i < 8; ++i) {
        float4 ep = *reinterpret_cast<const float4*>(&Es[16 * i + ty][nn]);
        acc[i][0] = fmaf(ep.x, v0.x, fmaf(ep.y, v1.x, fmaf(ep.z, v2.x, fmaf(ep.w, v3.x, acc[i][0]))));
        acc[i][1] = fmaf(ep.x, v0.y, fmaf(ep.y, v1.y, fmaf(ep.z, v2.y, fmaf(ep.w, v3.y, acc[i][1]))));
        acc[i][2] = fmaf(ep.x, v0.z, fmaf(ep.y, v1.z, fmaf(ep.z, v2.z, fmaf(ep.w, v3.z, acc[i][2]))));
        acc[i][3] = fmaf(ep.x, v0.w, fmaf(ep.y, v1.w, fmaf(ep.z, v2.w, fmaf(ep.w, v3.w, acc[i][3]))));
      }
    }
  }

#pragma unroll
  for (int d = 1; d < 16; d <<= 1)
#pragma unroll
    for (int i = 0; i < 8; ++i)
      norm[i] += __shfl_xor(norm[i], d, 64);

  float* Og = O + (size_t)m * BMQ * D_MODEL + h * DHEAD;
#pragma unroll
  for (int i = 0; i < 8; ++i) {
    int r = 16 * i + ty;
    float inv = 1.f / fmaxf(norm[i], EPSF);
    float4 o;
    o.x = acc[i][0] * inv;
    o.y = acc[i][1] * inv;
    o.z = acc[i][2] * inv;
    o.w = acc[i][3] * inv;
    *reinterpret_cast<float4*>(&Og[(size_t)r * D_MODEL + tx * 4]) = o;
  }
}

// ---------------------------------------------------------------------------
extern "C" void kernel_launch(void* const* d_in, const int* in_sizes, int n_in,
                              void* d_out, int out_size, void* d_ws, size_t ws_size,
                              hipStream_t stream) {
  (void)in_sizes; (void)n_in; (void)out_size;
  const float* x  = (const float*)d_in[0];
  const float* c  = (const float*)d_in[1];
  const float* Wq = (const float*)d_in[2];
  const float* bq = (const float*)d_in[3];
  const float* Wk = (const float*)d_in[4];
  const float* bk = (const float*)d_in[5];
  const float* Wv = (const float*)d_in[6];
  const float* bv = (const float*)d_in[7];
  const float* Wo = (const float*)d_in[8];
  const float* bo = (const float*)d_in[9];
  float* out = (float*)d_out;

  const size_t nqkv = (size_t)NSEQ * D_MODEL;            // 1,048,576 floats
  float* Q = (float*)d_ws;
  float* K = Q + nqkv;
  float* V = K + nqkv;
  float* O = V + nqkv;
  float* Opart = O + nqkv;                               // 1088 * 8192 floats
  float* Npart = Opart + (size_t)NHEADS * NPAIR * BMQ * DHEAD;  // 1088 * 128

  const size_t need_bytes =
      (4 * nqkv + (size_t)NHEADS * NPAIR * BMQ * DHEAD + (size_t)NHEADS * NPAIR * BMQ) * sizeof(float);

  qkv_kernel<<<dim3(D_MODEL / 64, NSEQ / 64, 3), 256, 0, stream>>>(
      x, Wq, bq, Wk, bk, Wv, bv, Q, K, V);

  if (ws_size >= need_bytes) {
    attn_pair_kernel<<<dim3(NPAIR, NHEADS), 512, 0, stream>>>(Q, K, V, c, Opart, Npart);
    reduce_kernel<<<dim3(NBLKS, NHEADS), 256, 0, stream>>>(Opart, Npart, O);
  } else {
    attn_kernel<<<dim3(NBLKS, NHEADS), 256, 0, stream>>>(Q, K, V, c, O);
  }

  oproj_kernel<<<dim3(D_MODEL / 64, NSEQ / 64), 256, 0, stream>>>(O, Wo, bo, out);
}

// Round 3
// 148.451 us; speedup vs baseline: 4.9698x; 2.3453x over previous
//
#include <hip/hip_runtime.h>
#include <math.h>

#define D_MODEL 512
#define NHEADS  8
#define DHEAD   64
#define NSEQ    2048
#define NBLK    16
#define NCHUNK  72          // sum over m of (m/2+1): chunks of <=2 kv-blocks
#define EPSF    1e-6f

typedef short v8s __attribute__((ext_vector_type(8)));
typedef float v4f __attribute__((ext_vector_type(4)));

static __device__ __forceinline__ v4f mfma16(v8s a, v8s b, v4f c) {
  return __builtin_amdgcn_mfma_f32_16x16x32_bf16(a, b, c, 0, 0, 0);
}
static __device__ __forceinline__ uint32_t bf16rne(float f) {
  uint32_t u = __float_as_uint(f);
  return (u + 0x7fffu + ((u >> 16) & 1u)) >> 16;
}
static __device__ __forceinline__ float bf16f(uint32_t h) {
  return __uint_as_float(h << 16);
}
// pack float into (lo16<<16)|hi16 bf16 pair; hi+lo reconstructs to ~2^-16 rel
static __device__ __forceinline__ uint32_t pack_hl(float f) {
  uint32_t hi = bf16rne(f);
  uint32_t lo = bf16rne(f - bf16f(hi));
  return hi | (lo << 16);
}

// ---------------------------------------------------------------------------
// x (fp32) -> interleaved hi/lo bf16 u32, same layout
__global__ __launch_bounds__(256) void prep_x(const float* __restrict__ x,
                                              uint32_t* __restrict__ xhl) {
  int idx = blockIdx.x * 256 + threadIdx.x;      // float4 index
  const float4 v = reinterpret_cast<const float4*>(x)[idx];
  uint4 o;
  o.x = pack_hl(v.x); o.y = pack_hl(v.y); o.z = pack_hl(v.z); o.w = pack_hl(v.w);
  reinterpret_cast<uint4*>(xhl)[idx] = o;
}

// W[k][n] fp32 -> Wt[n][k] interleaved hi/lo u32 (4 matrices, 64x64 tiles)
__global__ __launch_bounds__(256) void prep_w(const float* __restrict__ W0,
                                              const float* __restrict__ W1,
                                              const float* __restrict__ W2,
                                              const float* __restrict__ W3,
                                              uint32_t* __restrict__ Wthl) {
  __shared__ float T[64][68];
  const int z = blockIdx.z;
  const float* W = (z == 0) ? W0 : (z == 1) ? W1 : (z == 2) ? W2 : W3;
  const int kb = blockIdx.x * 64;
  const int nb = blockIdx.y * 64;
  const int tid = threadIdx.x;
#pragma unroll
  for (int l = 0; l < 4; ++l) {
    int f = tid + l * 256;           // 64 rows(k) x 16 float4(n)
    int row = f >> 4, c4 = f & 15;
    float4 v = *reinterpret_cast<const float4*>(&W[(size_t)(kb + row) * D_MODEL + nb + c4 * 4]);
    T[c4 * 4 + 0][row] = v.x; T[c4 * 4 + 1][row] = v.y;
    T[c4 * 4 + 2][row] = v.z; T[c4 * 4 + 3][row] = v.w;
  }
  __syncthreads();
  uint32_t* out = Wthl + (size_t)z * D_MODEL * D_MODEL;
#pragma unroll
  for (int l = 0; l < 4; ++l) {
    int f = tid + l * 256;           // 64 rows(n) x 16 float4(k)
    int n = f >> 4, k4 = f & 15;
    float4 v = *reinterpret_cast<const float4*>(&T[n][k4 * 4]);
    uint4 o;
    o.x = pack_hl(v.x); o.y = pack_hl(v.y); o.z = pack_hl(v.z); o.w = pack_hl(v.w);
    *reinterpret_cast<uint4*>(&out[(size_t)(nb + n) * D_MODEL + kb + k4 * 4]) = o;
  }
}

// ---------------------------------------------------------------------------
// MFMA GEMM: C[128x128] = A @ Wt^T + bias via 3-term hi/lo bf16.
// A,Bt interleaved u32. 256 threads = 4 waves, wave = 64x64 quadrant.
template <bool OUT_HL>
__device__ __forceinline__ void gemm_hl_body(const uint32_t* __restrict__ Ahl,
                                             const uint32_t* __restrict__ Bt,
                                             const float* __restrict__ bias,
                                             uint32_t* __restrict__ outU,
                                             float* __restrict__ outF) {
  __shared__ ushort Ah[128][40], Al[128][40], Bh[128][40], Bl[128][40];
  const int bx = blockIdx.x, by = blockIdx.y;
  const int tid = threadIdx.x;
  const int wid = tid >> 6, lane = tid & 63;
  const int wr = wid >> 1, wc = wid & 1;
  const int g = lane >> 4, lx = lane & 15;

  v4f acc[4][4];
#pragma unroll
  for (int i = 0; i < 4; ++i)
#pragma unroll
    for (int j = 0; j < 4; ++j) acc[i][j] = v4f{0.f, 0.f, 0.f, 0.f};

  for (int k0 = 0; k0 < 16; ++k0) {     // K = 512, step 32
    __syncthreads();
#pragma unroll
    for (int l = 0; l < 4; ++l) {
      int f = tid + l * 256;            // 128 rows x 8 uint4
      int row = f >> 3, c4 = f & 7;
      uint4 wa = *reinterpret_cast<const uint4*>(&Ahl[(size_t)(by * 128 + row) * D_MODEL + k0 * 32 + c4 * 4]);
      uint2 hh, ll;
      hh.x = (wa.x & 0xffffu) | (wa.y << 16); hh.y = (wa.z & 0xffffu) | (wa.w << 16);
      ll.x = (wa.x >> 16) | (wa.y & 0xffff0000u); ll.y = (wa.z >> 16) | (wa.w & 0xffff0000u);
      *reinterpret_cast<uint2*>(&Ah[row][c4 * 4]) = hh;
      *reinterpret_cast<uint2*>(&Al[row][c4 * 4]) = ll;
      uint4 wb = *reinterpret_cast<const uint4*>(&Bt[(size_t)(bx * 128 + row) * D_MODEL + k0 * 32 + c4 * 4]);
      hh.x = (wb.x & 0xffffu) | (wb.y << 16); hh.y = (wb.z & 0xffffu) | (wb.w << 16);
      ll.x = (wb.x >> 16) | (wb.y & 0xffff0000u); ll.y = (wb.z >> 16) | (wb.w & 0xffff0000u);
      *reinterpret_cast<uint2*>(&Bh[row][c4 * 4]) = hh;
      *reinterpret_cast<uint2*>(&Bl[row][c4 * 4]) = ll;
    }
    __syncthreads();
    v8s ah[4], al[4], bh[4], bl[4];
#pragma unroll
    for (int i = 0; i < 4; ++i) {
      ah[i] = *reinterpret_cast<const v8s*>(&Ah[wr * 64 + i * 16 + lx][g * 8]);
      al[i] = *reinterpret_cast<const v8s*>(&Al[wr * 64 + i * 16 + lx][g * 8]);
      bh[i] = *reinterpret_cast<const v8s*>(&Bh[wc * 64 + i * 16 + lx][g * 8]);
      bl[i] = *reinterpret_cast<const v8s*>(&Bl[wc * 64 + i * 16 + lx][g * 8]);
    }
#pragma unroll
    for (int i = 0; i < 4; ++i)
#pragma unroll
      for (int j = 0; j < 4; ++j) {
        acc[i][j] = mfma16(ah[i], bh[j], acc[i][j]);
        acc[i][j] = mfma16(ah[i], bl[j], acc[i][j]);
        acc[i][j] = mfma16(al[i], bh[j], acc[i][j]);
      }
  }
#pragma unroll
  for (int j = 0; j < 4; ++j) {
    const int col = bx * 128 + wc * 64 + j * 16 + lx;
    const float bj = bias[col];
#pragma unroll
    for (int i = 0; i < 4; ++i)
#pragma unroll
      for (int r = 0; r < 4; ++r) {
        const int row = by * 128 + wr * 64 + i * 16 + g * 4 + r;
        float v = acc[i][j][r] + bj;
        if (OUT_HL) outU[(size_t)row * D_MODEL + col] = pack_hl(v);
        else        outF[(size_t)row * D_MODEL + col] = v;
      }
  }
}

__global__ __launch_bounds__(256) void qkv_gemm(const uint32_t* __restrict__ xhl,
                                                const uint32_t* __restrict__ Wthl,
                                                const float* __restrict__ bq,
                                                const float* __restrict__ bk,
                                                const float* __restrict__ bv,
                                                uint32_t* __restrict__ Qhl,
                                                uint32_t* __restrict__ Khl,
                                                uint32_t* __restrict__ Vhl) {
  const int z = blockIdx.z;
  const float* bias = (z == 0) ? bq : (z == 1) ? bk : bv;
  uint32_t* out = (z == 0) ? Qhl : (z == 1) ? Khl : Vhl;
  gemm_hl_body<true>(xhl, Wthl + (size_t)z * D_MODEL * D_MODEL, bias, out, nullptr);
}

__global__ __launch_bounds__(256) void o_gemm(const uint32_t* __restrict__ Ohl,
                                              const uint32_t* __restrict__ Wthl,
                                              const float* __restrict__ bo,
                                              float* __restrict__ out) {
  gemm_hl_body<false>(Ohl, Wthl + (size_t)3 * D_MODEL * D_MODEL, bo, nullptr, out);
}

// ---------------------------------------------------------------------------
// V (interleaved hi/lo) -> Vtb[h][d][n] bf16-hi only, transposed per head
__global__ __launch_bounds__(256) void vt_prep(const uint32_t* __restrict__ Vhl,
                                               ushort* __restrict__ Vtb) {
  __shared__ uint32_t TV[64][68];
  const int nb = blockIdx.x * 64;
  const int h  = blockIdx.y;
  const int tid = threadIdx.x;
#pragma unroll
  for (int l = 0; l < 4; ++l) {
    int f = tid + l * 256;            // 64 rows(n) x 16 uint4(d)
    int row = f >> 4, c4 = f & 15;
    uint4 v = *reinterpret_cast<const uint4*>(&Vhl[(size_t)(nb + row) * D_MODEL + h * 64 + c4 * 4]);
    TV[c4 * 4 + 0][row] = v.x; TV[c4 * 4 + 1][row] = v.y;
    TV[c4 * 4 + 2][row] = v.z; TV[c4 * 4 + 3][row] = v.w;
  }
  __syncthreads();
#pragma unroll
  for (int l = 0; l < 4; ++l) {
    int f = tid + l * 256;            // 64 rows(d) x 16 x4(n)
    int d = f >> 4, n4 = f & 15;
    uint32_t a = TV[d][n4 * 4 + 0], b = TV[d][n4 * 4 + 1];
    uint32_t c = TV[d][n4 * 4 + 2], e = TV[d][n4 * 4 + 3];
    ushort4 o = make_ushort4((ushort)(a & 0xffffu), (ushort)(b & 0xffffu),
                             (ushort)(c & 0xffffu), (ushort)(e & 0xffffu));
    *reinterpret_cast<ushort4*>(&Vtb[(size_t)(h * 64 + d) * NSEQ + nb + n4 * 4]) = o;
  }
}

// ---------------------------------------------------------------------------
// Attention over chunks of <=2 kv-blocks. 512 threads = 8 waves; wave w owns
// q-rows [16w,16w+16). All softmax/E traffic is wave-local.
__global__ __launch_bounds__(512, 1) void attn_pair(
    const uint32_t* __restrict__ Qhl, const uint32_t* __restrict__ Khl,
    const ushort* __restrict__ Vtb, const float* __restrict__ cptr,
    float* __restrict__ Opart, float* __restrict__ Npart)
{
  __shared__ ushort Qhi[128][72], Qlo[128][72], Khi[128][72], Klo[128][72];
  __shared__ ushort Es[128][136];
  __shared__ ushort Vt[64][136];
  __shared__ float qn_s[128], kn_s[128];

  const int pid2 = blockIdx.x;      // 0..NCHUNK-1
  const int h    = blockIdx.y;
  int m = 0, base = 0;
  while (base + (m / 2 + 1) <= pid2) { base += m / 2 + 1; ++m; }
  const int c  = pid2 - base;
  const int n0 = 2 * c;
  const int n1 = (n0 + 1 < m) ? n0 + 1 : m;

  const int tid  = threadIdx.x;
  const int w    = tid >> 6;
  const int lane = tid & 63;
  const int g = lane >> 4, lx = lane & 15;

  const float cc = fmaxf(fabsf(cptr[0]), 1e-6f);
  const float inv_sqrt_c = rsqrtf(cc);
  const float two_cc = 2.f * cc;

  // ---- stage Q tile (hi/lo) ----
  {
    const uint32_t* Qg = Qhl + (size_t)(m * 128) * D_MODEL + h * 64;
#pragma unroll
    for (int l = 0; l < 4; ++l) {
      int f = tid + l * 512;          // 128 rows x 16 uint4
      int row = f >> 4, c4 = f & 15;
      uint4 wv = *reinterpret_cast<const uint4*>(&Qg[(size_t)row * D_MODEL + c4 * 4]);
      uint2 hh, ll;
      hh.x = (wv.x & 0xffffu) | (wv.y << 16); hh.y = (wv.z & 0xffffu) | (wv.w << 16);
      ll.x = (wv.x >> 16) | (wv.y & 0xffff0000u); ll.y = (wv.z >> 16) | (wv.w & 0xffff0000u);
      *reinterpret_cast<uint2*>(&Qhi[row][c4 * 4]) = hh;
      *reinterpret_cast<uint2*>(&Qlo[row][c4 * 4]) = ll;
    }
  }
  __syncthreads();

  // ---- q norms (wave-local rows) ----
  {
    float qs = 0.f;
    const int row = 16 * w + lx;
#pragma unroll
    for (int ks = 0; ks < 2; ++ks) {
      v8s qh = *reinterpret_cast<const v8s*>(&Qhi[row][g * 8 + ks * 32]);
      v8s ql = *reinterpret_cast<const v8s*>(&Qlo[row][g * 8 + ks * 32]);
#pragma unroll
      for (int j = 0; j < 8; ++j) {
        float qv = bf16f((uint32_t)(ushort)qh[j]) + bf16f((uint32_t)(ushort)ql[j]);
        qs = fmaf(qv, qv, qs);
      }
    }
    qs += __shfl_xor(qs, 16, 64);
    qs += __shfl_xor(qs, 32, 64);
    if (lane < 16) qn_s[16 * w + lx] = qs;
  }

  // persistent A fragments (Q rows of this wave)
  v8s aQh[2], aQl[2];
#pragma unroll
  for (int ks = 0; ks < 2; ++ks) {
    aQh[ks] = *reinterpret_cast<const v8s*>(&Qhi[16 * w + lx][g * 8 + ks * 32]);
    aQl[ks] = *reinterpret_cast<const v8s*>(&Qlo[16 * w + lx][g * 8 + ks * 32]);
  }
  float qnr[4], qar[4];
#pragma unroll
  for (int r = 0; r < 4; ++r) {
    qnr[r] = qn_s[16 * w + g * 4 + r];       // written by this wave
    qar[r] = fmaf(-cc, qnr[r], 1.f);
  }

  v4f o_acc[4];
#pragma unroll
  for (int td = 0; td < 4; ++td) o_acc[td] = v4f{0.f, 0.f, 0.f, 0.f};
  float nrm[4] = {0.f, 0.f, 0.f, 0.f};

  for (int n = n0; n <= n1; ++n) {
    __syncthreads();                  // previous K/V/kn readers done
    // ---- stage K (hi/lo) + Vt (bf16) ----
    {
      const uint32_t* Kg = Khl + (size_t)(n * 128) * D_MODEL + h * 64;
#pragma unroll
      for (int l = 0; l < 4; ++l) {
        int f = tid + l * 512;
        int row = f >> 4, c4 = f & 15;
        uint4 wv = *reinterpret_cast<const uint4*>(&Kg[(size_t)row * D_MODEL + c4 * 4]);
        uint2 hh, ll;
        hh.x = (wv.x & 0xffffu) | (wv.y << 16); hh.y = (wv.z & 0xffffu) | (wv.w << 16);
        ll.x = (wv.x >> 16) | (wv.y & 0xffff0000u); ll.y = (wv.z >> 16) | (wv.w & 0xffff0000u);
        *reinterpret_cast<uint2*>(&Khi[row][c4 * 4]) = hh;
        *reinterpret_cast<uint2*>(&Klo[row][c4 * 4]) = ll;
      }
      const ushort* Vg = Vtb + (size_t)(h * 64) * NSEQ + n * 128;
#pragma unroll
      for (int l = 0; l < 2; ++l) {
        int f = tid + l * 512;        // 64 rows(d) x 16 groups of 8 bf16
        int d = f >> 4, c8 = f & 15;
        uint4 vv = *reinterpret_cast<const uint4*>(&Vg[(size_t)d * NSEQ + c8 * 8]);
        *reinterpret_cast<uint4*>(&Vt[d][c8 * 8]) = vv;
      }
    }
    __syncthreads();
    // ---- k norms ----
    {
      float ksum = 0.f;
      const int row = 16 * w + lx;
#pragma unroll
      for (int ks = 0; ks < 2; ++ks) {
        v8s kh = *reinterpret_cast<const v8s*>(&Khi[row][g * 8 + ks * 32]);
        v8s kl = *reinterpret_cast<const v8s*>(&Klo[row][g * 8 + ks * 32]);
#pragma unroll
        for (int j = 0; j < 8; ++j) {
          float kv = bf16f((uint32_t)(ushort)kh[j]) + bf16f((uint32_t)(ushort)kl[j]);
          ksum = fmaf(kv, kv, ksum);
        }
      }
      ksum += __shfl_xor(ksum, 16, 64);
      ksum += __shfl_xor(ksum, 32, 64);
      if (lane < 16) kn_s[16 * w + lx] = ksum;
    }
    __syncthreads();                  // kn_s visible to all waves

    // ---- S = Q.K^T via 3-term hi/lo MFMA ----
    v4f acc[8];
#pragma unroll
    for (int tn = 0; tn < 8; ++tn) acc[tn] = v4f{0.f, 0.f, 0.f, 0.f};
#pragma unroll
    for (int tn = 0; tn < 8; ++tn) {
      v8s bh0 = *reinterpret_cast<const v8s*>(&Khi[tn * 16 + lx][g * 8]);
      v8s bh1 = *reinterpret_cast<const v8s*>(&Khi[tn * 16 + lx][g * 8 + 32]);
      v8s bl0 = *reinterpret_cast<const v8s*>(&Klo[tn * 16 + lx][g * 8]);
      v8s bl1 = *reinterpret_cast<const v8s*>(&Klo[tn * 16 + lx][g * 8 + 32]);
      acc[tn] = mfma16(aQh[0], bh0, acc[tn]);
      acc[tn] = mfma16(aQh[1], bh1, acc[tn]);
      acc[tn] = mfma16(aQh[0], bl0, acc[tn]);
      acc[tn] = mfma16(aQh[1], bl1, acc[tn]);
      acc[tn] = mfma16(aQl[0], bh0, acc[tn]);
      acc[tn] = mfma16(aQl[1], bh1, acc[tn]);
    }

    // ---- Poincare scores + diag mask + per-block row max ----
    const bool diag = (n == m);
    float mrow[4] = {-INFINITY, -INFINITY, -INFINITY, -INFINITY};
#pragma unroll
    for (int tn = 0; tn < 8; ++tn) {
      const int col = tn * 16 + lx;
      const float knc = kn_s[col];
      const float kac = fmaf(-cc, knc, 1.f);
#pragma unroll
      for (int r = 0; r < 4; ++r) {
        const int rowl = 16 * w + g * 4 + r;
        float dsq = fmaxf(fmaf(-2.f, acc[tn][r], qnr[r] + knc), 0.f);
        float den = fmaxf(qar[r] * kac, EPSF);
        float t = fmaxf(two_cc * dsq / den, EPSF);
        float sc = -__logf(1.f + t + __fsqrt_rn(t * (t + 2.f))) * inv_sqrt_c;
        if (diag && col > rowl) sc = -INFINITY;
        acc[tn][r] = sc;
        mrow[r] = fmaxf(mrow[r], sc);
      }
    }
#pragma unroll
    for (int d = 1; d < 16; d <<= 1)
#pragma unroll
      for (int r = 0; r < 4; ++r)
        mrow[r] = fmaxf(mrow[r], __shfl_xor(mrow[r], d, 64));

    // ---- e = exp(s - bmax) -> Es (bf16, wave-local rows), norm accum ----
#pragma unroll
    for (int tn = 0; tn < 8; ++tn) {
#pragma unroll
      for (int r = 0; r < 4; ++r) {
        float e = __expf(acc[tn][r] - mrow[r]);
        nrm[r] += e;
        Es[16 * w + g * 4 + r][tn * 16 + lx] = (ushort)bf16rne(e);
      }
    }
    __syncthreads();                  // safety: E writes drained

    // ---- o += E @ V ----
#pragma unroll
    for (int ks = 0; ks < 4; ++ks) {
      v8s ea = *reinterpret_cast<const v8s*>(&Es[16 * w + lx][ks * 32 + g * 8]);
#pragma unroll
      for (int td = 0; td < 4; ++td) {
        v8s vb = *reinterpret_cast<const v8s*>(&Vt[td * 16 + lx][ks * 32 + g * 8]);
        o_acc[td] = mfma16(ea, vb, o_acc[td]);
      }
    }
  }

  // ---- norm reduce + store partials ----
#pragma unroll
  for (int d = 1; d < 16; d <<= 1)
#pragma unroll
    for (int r = 0; r < 4; ++r)
      nrm[r] += __shfl_xor(nrm[r], d, 64);

  float* Op = Opart + ((size_t)h * NCHUNK + pid2) * (128 * 64);
#pragma unroll
  for (int td = 0; td < 4; ++td)
#pragma unroll
    for (int r = 0; r < 4; ++r)
      Op[(size_t)(16 * w + g * 4 + r) * 64 + td * 16 + lx] = o_acc[td][r];
  if (lx == 0) {
#pragma unroll
    for (int r = 0; r < 4; ++r)
      Npart[((size_t)h * NCHUNK + pid2) * 128 + 16 * w + g * 4 + r] = nrm[r];
  }
}

// ---------------------------------------------------------------------------
// Sum partials over chunks, normalize, emit interleaved hi/lo for o_gemm.
__global__ __launch_bounds__(256) void reduce_o(const float* __restrict__ Opart,
                                                const float* __restrict__ Npart,
                                                uint32_t* __restrict__ Ohl) {
  const int mm = blockIdx.x;
  const int h  = blockIdx.y;
  const int tid = threadIdx.x;
  int base = 0;
  for (int k = 0; k < mm; ++k) base += k / 2 + 1;
  const int nch = mm / 2 + 1;

  __shared__ float innorm[128];
  if (tid < 128) {
    float s = 0.f;
    for (int cI = 0; cI < nch; ++cI)
      s += Npart[((size_t)h * NCHUNK + base + cI) * 128 + tid];
    innorm[tid] = 1.f / fmaxf(s, EPSF);
  }
  __syncthreads();
#pragma unroll
  for (int l = 0; l < 8; ++l) {
    int f = tid + l * 256;            // 128 rows x 16 float4
    int r = f >> 4, c4 = f & 15;
    float4 s = {0.f, 0.f, 0.f, 0.f};
    for (int cI = 0; cI < nch; ++cI) {
      const float4 p = *reinterpret_cast<const float4*>(
          &Opart[((size_t)h * NCHUNK + base + cI) * 8192 + (size_t)r * 64 + c4 * 4]);
      s.x += p.x; s.y += p.y; s.z += p.z; s.w += p.w;
    }
    float inv = innorm[r];
    uint4 o;
    o.x = pack_hl(s.x * inv); o.y = pack_hl(s.y * inv);
    o.z = pack_hl(s.z * inv); o.w = pack_hl(s.w * inv);
    *reinterpret_cast<uint4*>(&Ohl[(size_t)(mm * 128 + r) * D_MODEL + h * 64 + c4 * 4]) = o;
  }
}

// ---------------------------------------------------------------------------
extern "C" void kernel_launch(void* const* d_in, const int* in_sizes, int n_in,
                              void* d_out, int out_size, void* d_ws, size_t ws_size,
                              hipStream_t stream) {
  (void)in_sizes; (void)n_in; (void)out_size; (void)ws_size;
  const float* x  = (const float*)d_in[0];
  const float* cfg= (const float*)d_in[1];
  const float* Wq = (const float*)d_in[2];
  const float* bq = (const float*)d_in[3];
  const float* Wk = (const float*)d_in[4];
  const float* bk = (const float*)d_in[5];
  const float* Wv = (const float*)d_in[6];
  const float* bv = (const float*)d_in[7];
  const float* Wo = (const float*)d_in[8];
  const float* bo = (const float*)d_in[9];
  float* out = (float*)d_out;

  const size_t NQ = (size_t)NSEQ * D_MODEL;        // 1,048,576
  uint32_t* ws   = (uint32_t*)d_ws;
  uint32_t* xhl  = ws;
  uint32_t* Wthl = ws + NQ;
  uint32_t* Qhl  = ws + 2 * NQ;
  uint32_t* Khl  = ws + 3 * NQ;
  uint32_t* Vhl  = ws + 4 * NQ;
  ushort*   Vtb  = (ushort*)(ws + 5 * NQ);         // NQ/2 u32 worth
  uint32_t* Ohl  = ws + 5 * NQ + NQ / 2;
  float*    Opart= (float*)(ws + 6 * NQ + NQ / 2);
  float*    Npart= Opart + (size_t)NHEADS * NCHUNK * 8192;

  prep_x<<<1024, 256, 0, stream>>>(x, xhl);
  prep_w<<<dim3(8, 8, 4), 256, 0, stream>>>(Wq, Wk, Wv, Wo, Wthl);
  qkv_gemm<<<dim3(4, 16, 3), 256, 0, stream>>>(xhl, Wthl, bq, bk, bv, Qhl, Khl, Vhl);
  vt_prep<<<dim3(32, 8), 256, 0, stream>>>(Vhl, Vtb);
  attn_pair<<<dim3(NCHUNK, NHEADS), 512, 0, stream>>>(Qhl, Khl, Vtb, cfg, Opart, Npart);
  reduce_o<<<dim3(NBLK, NHEADS), 256, 0, stream>>>(Opart, Npart, Ohl);
  o_gemm<<<dim3(4, 16), 256, 0, stream>>>(Ohl, Wthl, bo, out);
}